// Round 2
// baseline (1523.394 us; speedup 1.0000x reference)
//
#include <hip/hip_runtime.h>
#include <hip/hip_bf16.h>

typedef __attribute__((ext_vector_type(8))) __bf16 bf16x8;
typedef __attribute__((ext_vector_type(4))) float f32x4;

#define ACT_NONE 0
#define ACT_RELU 1
#define ACT_GELU 2
#define ACT_TANH 3
#define OUT_F32 0
#define OUT_BF16 1
#define OUT_ADD 2

// ---------------- implicit-GEMM A addressing ----------------
// MODE 0: plain row-major A[M][K]
// MODE 1: conv1 im2col: input (1920,84,84,4) f32, 8x8 s4 -> m=(img,oy,ox), k=ky*32+(kx*4+ci)
// MODE 2: conv2 im2col: input (1920,20,20,32), 4x4 s2 -> k=(ky*4+kx)*32+ci
// MODE 3: conv3 im2col: input (1920,9,9,64),  3x3 s1 -> k=(ky*3+kx)*64+ci
template<int MODE, int K>
__device__ __forceinline__ size_t a_rowbase(int m) {
  if constexpr (MODE == 0) {
    return (size_t)m * K;
  } else if constexpr (MODE == 1) {
    int img = m / 400; int p = m - img * 400; int oy = p / 20; int ox = p - oy * 20;
    return (size_t)img * 28224 + oy * 1344 + ox * 16;
  } else if constexpr (MODE == 2) {
    int img = m / 81; int p = m - img * 81; int oy = p / 9; int ox = p - oy * 9;
    return (size_t)img * 12800 + oy * 1280 + ox * 64;
  } else {
    int img = m / 49; int p = m - img * 49; int oy = p / 7; int ox = p - oy * 7;
    return (size_t)img * 5184 + oy * 576 + ox * 64;
  }
}
template<int MODE>
__device__ __forceinline__ int a_koff(int k) {
  if constexpr (MODE == 0) return k;
  else if constexpr (MODE == 1) return (k >> 5) * 336 + (k & 31);
  else if constexpr (MODE == 2) return (k >> 7) * 640 + ((k >> 5) & 3) * 32 + (k & 31);
  else { int ky = k / 192; int r = k - ky * 192; return ky * 576 + r; }
}

// load 8 contiguous elements as bf16x8; F32 path converts fp32->bf16
template<bool F32>
__device__ __forceinline__ bf16x8 ld8(const void* p) {
  if constexpr (F32) {
    const float* f = (const float*)p;
    float4 a = *(const float4*)f;
    float4 b = *(const float4*)(f + 4);
    bf16x8 r;
    r[0] = (__bf16)a.x; r[1] = (__bf16)a.y; r[2] = (__bf16)a.z; r[3] = (__bf16)a.w;
    r[4] = (__bf16)b.x; r[5] = (__bf16)b.y; r[6] = (__bf16)b.z; r[7] = (__bf16)b.w;
    return r;
  } else {
    return *(const bf16x8*)p;
  }
}

// ---------------- generic MFMA GEMM:  C[M][N] = act(A * BT^T + bias) ----------------
// A: bf16 or f32 (AF32), addressed per MODE. BT: bf16 [Npad>=128][K] row-major.
// 128x128 tile, BK=32, 4 waves of 64x64 (4x4 MFMA 16x16x32). Register-staged LDS.
template<int MODE, bool AF32, int NREAL, int K, int ACT, int OUTM, int LDC>
__global__ __launch_bounds__(256) void gemm_k(const void* __restrict__ Av,
                                              const __bf16* __restrict__ BT,
                                              const float* __restrict__ bias,
                                              void* __restrict__ C) {
  constexpr int LDAS = 48;  // padded LDS row stride (elems)
  __shared__ __bf16 As[128 * LDAS];
  __shared__ __bf16 Bs[128 * LDAS];
  const __bf16* Ab = (const __bf16*)Av;
  const float* Af = (const float*)Av;
  const int tid = threadIdx.x;
  const int wave = tid >> 6, lane = tid & 63;
  const int quad = lane >> 4, l16 = lane & 15;
  const int wr = wave >> 1, wc = wave & 1;
  const int m0 = blockIdx.x * 128, n0 = blockIdx.y * 128;

  // staging: 512 chunks of 8 elems per matrix; thread owns chunks tid and tid+256
  const int c0 = tid, c1 = tid + 256;
  const int r0 = c0 >> 2, k0o = (c0 & 3) * 8;
  const int r1 = c1 >> 2, k1o = (c1 & 3) * 8;
  const size_t ar0 = a_rowbase<MODE, K>(m0 + r0);
  const size_t ar1 = a_rowbase<MODE, K>(m0 + r1);
  const size_t br0 = (size_t)(n0 + r0) * K;
  const size_t br1 = (size_t)(n0 + r1) * K;

  auto aptr = [&](size_t idx) -> const void* {
    if constexpr (AF32) return (const void*)(Af + idx);
    else return (const void*)(Ab + idx);
  };

  f32x4 acc[4][4] = {};
  bf16x8 av0 = ld8<AF32>(aptr(ar0 + a_koff<MODE>(k0o)));
  bf16x8 av1 = ld8<AF32>(aptr(ar1 + a_koff<MODE>(k1o)));
  bf16x8 bv0 = *(const bf16x8*)(BT + br0 + k0o);
  bf16x8 bv1 = *(const bf16x8*)(BT + br1 + k1o);

  constexpr int NK = K / 32;
  for (int kt = 0; kt < NK; ++kt) {
    __syncthreads();
    *(bf16x8*)&As[r0 * LDAS + k0o] = av0;
    *(bf16x8*)&As[r1 * LDAS + k1o] = av1;
    *(bf16x8*)&Bs[r0 * LDAS + k0o] = bv0;
    *(bf16x8*)&Bs[r1 * LDAS + k1o] = bv1;
    __syncthreads();
    if (kt + 1 < NK) {
      const int kb = (kt + 1) * 32;
      av0 = ld8<AF32>(aptr(ar0 + a_koff<MODE>(kb + k0o)));
      av1 = ld8<AF32>(aptr(ar1 + a_koff<MODE>(kb + k1o)));
      bv0 = *(const bf16x8*)(BT + br0 + kb + k0o);
      bv1 = *(const bf16x8*)(BT + br1 + kb + k1o);
    }
    bf16x8 af[4], bfv[4];
#pragma unroll
    for (int mt = 0; mt < 4; ++mt)
      af[mt] = *(const bf16x8*)&As[(wr * 64 + mt * 16 + l16) * LDAS + quad * 8];
#pragma unroll
    for (int nt = 0; nt < 4; ++nt)
      bfv[nt] = *(const bf16x8*)&Bs[(wc * 64 + nt * 16 + l16) * LDAS + quad * 8];
#pragma unroll
    for (int mt = 0; mt < 4; ++mt)
#pragma unroll
      for (int nt = 0; nt < 4; ++nt)
        acc[mt][nt] = __builtin_amdgcn_mfma_f32_16x16x32_bf16(af[mt], bfv[nt], acc[mt][nt], 0, 0, 0);
  }

  // epilogue: C/D layout col=lane&15, row=quad*4+reg
#pragma unroll
  for (int nt = 0; nt < 4; ++nt) {
    const int col = n0 + wc * 64 + nt * 16 + l16;
    if (col < NREAL) {
      const float bvl = bias[col];
#pragma unroll
      for (int mt = 0; mt < 4; ++mt) {
#pragma unroll
        for (int r = 0; r < 4; ++r) {
          const int row = m0 + wr * 64 + mt * 16 + quad * 4 + r;
          float v = acc[mt][nt][r] + bvl;
          if constexpr (ACT == ACT_RELU) v = fmaxf(v, 0.f);
          else if constexpr (ACT == ACT_GELU) v = 0.5f * v * (1.f + erff(v * 0.70710678118f));
          else if constexpr (ACT == ACT_TANH) v = tanhf(v);
          const size_t off = (size_t)row * LDC + col;
          if constexpr (OUTM == OUT_F32) ((float*)C)[off] = v;
          else if constexpr (OUTM == OUT_BF16) ((__bf16*)C)[off] = (__bf16)v;
          else ((float*)C)[off] += v;
        }
      }
    }
  }
}

// ---------------- transpose + pad (+scale): dst[Cpad][R] = src[R][C]^T, f32 src ----------------
template<typename TO>
__global__ void transpose_pad(const float* __restrict__ src, TO* __restrict__ dst,
                              int R, int C, int Cpad, long long sz, long long dz, float scale) {
  src += blockIdx.z * sz; dst += blockIdx.z * dz;
  __shared__ float t[32][33];
  const int tx = threadIdx.x, ty = threadIdx.y;
  const int r0 = blockIdx.x * 32, c0 = blockIdx.y * 32;
  for (int i = ty; i < 32; i += 8) {
    int r = r0 + i, c = c0 + tx;
    t[i][tx] = (r < R && c < C) ? src[(size_t)r * C + c] : 0.f;
  }
  __syncthreads();
  for (int i = ty; i < 32; i += 8) {
    int c = c0 + i, r = r0 + tx;
    if (c < Cpad && r < R)
      dst[(size_t)c * R + r] = (c < C) ? (TO)(t[tx][i] * scale) : (TO)0.f;
  }
}

__global__ void biascat_k(const float* bk, const float* bq, const float* bv, float* dst) {
  const int i = blockIdx.x;
  for (int d = threadIdx.x; d < 512; d += 256) {
    dst[i * 1536 + d] = bk[i * 512 + d];
    dst[i * 1536 + 512 + d] = bq[i * 512 + d];
    dst[i * 1536 + 1024 + d] = bv[i * 512 + d];
  }
}

// ---------------- token embedding: x = interleave(rtg_e, st_e, a_e) + pos ----------------
__global__ void embed_k(const float* __restrict__ rtgs, const int* __restrict__ actions,
                        const int* __restrict__ timesteps, const float* __restrict__ W_rtg,
                        const float* __restrict__ b_rtg, const float* __restrict__ emb_a,
                        const float* __restrict__ abs_pos, const float* __restrict__ rel_pos,
                        const float* __restrict__ ste, float* __restrict__ x) {
  const int idx = blockIdx.x * 256 + threadIdx.x;  // 64*90*512 total
  const int d = idx & 511; const int rb = idx >> 9;
  const int b = rb / 90, t = rb - b * 90;
  const int l = t / 3, r = t - l * 3;
  const float pos = rel_pos[t * 512 + d] + abs_pos[(size_t)timesteps[b] * 512 + d];
  float tok;
  if (r == 0) tok = tanhf(rtgs[b * 30 + l] * W_rtg[d] + b_rtg[d]);
  else if (r == 1) tok = ste[(size_t)(b * 30 + l) * 512 + d];
  else tok = tanhf(emb_a[actions[b * 30 + l] * 512 + d]);
  x[idx] = tok + pos;
}

// ---------------- layernorm: h_bf16 = LN(x_f32) * g + b, one wave per row ----------------
__global__ __launch_bounds__(256) void ln_k(const float* __restrict__ x, const float* __restrict__ g,
                                            const float* __restrict__ bb, __bf16* __restrict__ h) {
  const int row = blockIdx.x * 4 + (threadIdx.x >> 6);
  const int lane = threadIdx.x & 63;
  const float* xr = x + (size_t)row * 512;
  float4 a = *(const float4*)&xr[lane * 8];
  float4 c = *(const float4*)&xr[lane * 8 + 4];
  float vv[8] = {a.x, a.y, a.z, a.w, c.x, c.y, c.z, c.w};
  float s = 0.f, q = 0.f;
#pragma unroll
  for (int j = 0; j < 8; ++j) { s += vv[j]; q += vv[j] * vv[j]; }
  for (int o = 32; o; o >>= 1) { s += __shfl_xor(s, o); q += __shfl_xor(q, o); }
  const float mean = s * (1.f / 512.f);
  const float var = q * (1.f / 512.f) - mean * mean;
  const float rstd = rsqrtf(var + 1e-3f);
  float4 g1 = *(const float4*)&g[lane * 8];
  float4 g2 = *(const float4*)&g[lane * 8 + 4];
  float4 b1 = *(const float4*)&bb[lane * 8];
  float4 b2 = *(const float4*)&bb[lane * 8 + 4];
  float gg[8] = {g1.x, g1.y, g1.z, g1.w, g2.x, g2.y, g2.z, g2.w};
  float bbv[8] = {b1.x, b1.y, b1.z, b1.w, b2.x, b2.y, b2.z, b2.w};
  bf16x8 ov;
#pragma unroll
  for (int j = 0; j < 8; ++j)
    ov[j] = (__bf16)((vv[j] - mean) * rstd * gg[j] + bbv[j]);
  *(bf16x8*)&h[(size_t)row * 512 + lane * 8] = ov;
}

// ---------------- fused attention per (b,h): s=K@Q^T/8 masked, softmax, o=W@V, x += o ----------------
__global__ __launch_bounds__(256) void attn_k(const __bf16* __restrict__ qkv, float* __restrict__ x) {
  __shared__ __align__(16) char smem[64512];
  __bf16* kS = (__bf16*)smem;              // [96][72]  13824B
  __bf16* qS = (__bf16*)(smem + 13824);    // [96][72]  13824B
  __bf16* wS = (__bf16*)smem;              // [96][104] 19968B (reuses k/q after scores)
  float* sS = (float*)(smem + 27648);      // [96][96]  36864B
  __bf16* vT = (__bf16*)(smem + 27648);    // [64][104] 13312B (reuses sS after softmax)

  const int tid = threadIdx.x;
  const int b = blockIdx.x >> 3, h = blockIdx.x & 7;
  const int wave = tid >> 6, lane = tid & 63, quad = lane >> 4, l16 = lane & 15;
  const size_t rowbase = (size_t)b * 90 * 1536 + h * 64;

  // phase 1: load K, Q tiles (zero-pad rows 90..95)
  for (int c = tid; c < 768; c += 256) {
    const int t = c >> 3, d8 = (c & 7) * 8;
    bf16x8 kv, qv;
#pragma unroll
    for (int j = 0; j < 8; ++j) { kv[j] = (__bf16)0.f; qv[j] = (__bf16)0.f; }
    if (t < 90) {
      const __bf16* src = qkv + rowbase + (size_t)t * 1536 + d8;
      kv = *(const bf16x8*)src;
      qv = *(const bf16x8*)(src + 512);
    }
    *(bf16x8*)&kS[t * 72 + d8] = kv;
    *(bf16x8*)&qS[t * 72 + d8] = qv;
  }
  __syncthreads();

  // phase 2: s[i][j] = sum_d k[i,d] q[j,d] / 8, causal mask j<=i
  for (int tt = wave; tt < 36; tt += 4) {
    const int it = tt / 6, jt = tt - it * 6;
    f32x4 acc = {0.f, 0.f, 0.f, 0.f};
#pragma unroll
    for (int ks = 0; ks < 2; ++ks) {
      bf16x8 af = *(const bf16x8*)&kS[(it * 16 + l16) * 72 + ks * 32 + quad * 8];
      bf16x8 bq = *(const bf16x8*)&qS[(jt * 16 + l16) * 72 + ks * 32 + quad * 8];
      acc = __builtin_amdgcn_mfma_f32_16x16x32_bf16(af, bq, acc, 0, 0, 0);
    }
    const int col = jt * 16 + l16;
#pragma unroll
    for (int r = 0; r < 4; ++r) {
      const int row = it * 16 + quad * 4 + r;
      sS[row * 96 + col] = (col <= row && col < 90) ? acc[r] * 0.125f : -1e30f;
    }
  }
  __syncthreads();

  // phase 3: row softmax -> wS (bf16)
  for (int row = wave; row < 96; row += 4) {
    const float e0 = sS[row * 96 + lane];
    const float e1 = (lane < 32) ? sS[row * 96 + 64 + lane] : -1e30f;
    float m = fmaxf(e0, e1);
    for (int o = 32; o; o >>= 1) m = fmaxf(m, __shfl_xor(m, o));
    const float p0 = __expf(e0 - m);
    const float p1 = (lane < 32) ? __expf(e1 - m) : 0.f;
    float s = p0 + p1;
    for (int o = 32; o; o >>= 1) s += __shfl_xor(s, o);
    const float inv = 1.f / s;
    wS[row * 104 + lane] = (__bf16)(p0 * inv);
    if (lane < 32) wS[row * 104 + 64 + lane] = (__bf16)(p1 * inv);
  }
  __syncthreads();

  // phase 4: load V transposed into vT[d][j] (zero-pad cols 90..95)
  for (int c = tid; c < 768; c += 256) {
    const int t = c >> 3, d8 = (c & 7) * 8;
    bf16x8 vv;
#pragma unroll
    for (int j = 0; j < 8; ++j) vv[j] = (__bf16)0.f;
    if (t < 90) vv = *(const bf16x8*)(qkv + rowbase + (size_t)t * 1536 + 1024 + d8);
#pragma unroll
    for (int j = 0; j < 8; ++j) vT[(d8 + j) * 104 + t] = vv[j];
  }
  __syncthreads();

  // phase 5: o[i][d] = sum_j w[i,j] v[j,d]; x[b, i, h*64+d] += o
  for (int tt = wave; tt < 24; tt += 4) {
    const int it = tt >> 2, dt = tt & 3;
    f32x4 acc = {0.f, 0.f, 0.f, 0.f};
#pragma unroll
    for (int ks = 0; ks < 3; ++ks) {
      bf16x8 aw = *(const bf16x8*)&wS[(it * 16 + l16) * 104 + ks * 32 + quad * 8];
      bf16x8 bv = *(const bf16x8*)&vT[(dt * 16 + l16) * 104 + ks * 32 + quad * 8];
      acc = __builtin_amdgcn_mfma_f32_16x16x32_bf16(aw, bv, acc, 0, 0, 0);
    }
    const int d = dt * 16 + l16;
#pragma unroll
    for (int r = 0; r < 4; ++r) {
      const int i = it * 16 + quad * 4 + r;
      if (i < 90) {
        float* p = x + (size_t)(b * 90 + i) * 512 + h * 64 + d;
        *p += acc[r];
      }
    }
  }
}

// ---------------- fused final LN + head (state tokens only), 1 wave per output row ----------------
__global__ __launch_bounds__(64) void head_k(const float* __restrict__ x, const float* __restrict__ g,
                                             const float* __restrict__ bb, const float* __restrict__ whT,
                                             float* __restrict__ out) {
  const int m = blockIdx.x;  // 0..1919 = b*30+l
  const int b = m / 30, l = m - b * 30;
  const float* xr = x + (size_t)(b * 90 + 3 * l + 1) * 512;
  const int lane = threadIdx.x;
  float4 a = *(const float4*)&xr[lane * 8];
  float4 c = *(const float4*)&xr[lane * 8 + 4];
  float vv[8] = {a.x, a.y, a.z, a.w, c.x, c.y, c.z, c.w};
  float s = 0.f, q = 0.f;
#pragma unroll
  for (int j = 0; j < 8; ++j) { s += vv[j]; q += vv[j] * vv[j]; }
  for (int o = 32; o; o >>= 1) { s += __shfl_xor(s, o); q += __shfl_xor(q, o); }
  const float mean = s * (1.f / 512.f);
  const float var = q * (1.f / 512.f) - mean * mean;
  const float rstd = rsqrtf(var + 1e-3f);
  float4 g1 = *(const float4*)&g[lane * 8];
  float4 g2 = *(const float4*)&g[lane * 8 + 4];
  float4 b1 = *(const float4*)&bb[lane * 8];
  float4 b2 = *(const float4*)&bb[lane * 8 + 4];
  float gg[8] = {g1.x, g1.y, g1.z, g1.w, g2.x, g2.y, g2.z, g2.w};
  float bbv[8] = {b1.x, b1.y, b1.z, b1.w, b2.x, b2.y, b2.z, b2.w};
#pragma unroll
  for (int j = 0; j < 8; ++j)
    vv[j] = (vv[j] - mean) * rstd * gg[j] + bbv[j];
  for (int aa = 0; aa < 18; ++aa) {
    float4 w1v = *(const float4*)&whT[aa * 512 + lane * 8];
    float4 w2v = *(const float4*)&whT[aa * 512 + lane * 8 + 4];
    float ww[8] = {w1v.x, w1v.y, w1v.z, w1v.w, w2v.x, w2v.y, w2v.z, w2v.w};
    float d = 0.f;
#pragma unroll
    for (int j = 0; j < 8; ++j) d += vv[j] * ww[j];
    for (int o = 32; o; o >>= 1) d += __shfl_xor(d, o);
    if (lane == 0) out[m * 18 + aa] = d;
  }
}

// ---------------- host ----------------
extern "C" void kernel_launch(void* const* d_in, const int* in_sizes, int n_in,
                              void* d_out, int out_size, void* d_ws, size_t ws_size,
                              hipStream_t stream) {
  const float* rtgs = (const float*)d_in[0];
  const float* states = (const float*)d_in[1];
  const int* actions = (const int*)d_in[2];
  const int* timesteps = (const int*)d_in[3];
  const float* W_rtg = (const float*)d_in[4];
  const float* b_rtg = (const float*)d_in[5];
  const float* conv1_w = (const float*)d_in[6];
  const float* conv1_b = (const float*)d_in[7];
  const float* conv2_w = (const float*)d_in[8];
  const float* conv2_b = (const float*)d_in[9];
  const float* conv3_w = (const float*)d_in[10];
  const float* conv3_b = (const float*)d_in[11];
  const float* dense_s_w = (const float*)d_in[12];
  const float* dense_s_b = (const float*)d_in[13];
  const float* emb_a = (const float*)d_in[14];
  const float* abs_pos = (const float*)d_in[15];
  const float* rel_pos = (const float*)d_in[16];
  const float* ln1_g = (const float*)d_in[17];
  const float* ln1_b = (const float*)d_in[18];
  const float* Wk = (const float*)d_in[19];
  const float* bk = (const float*)d_in[20];
  const float* Wq = (const float*)d_in[21];
  const float* bq = (const float*)d_in[22];
  const float* Wv = (const float*)d_in[23];
  const float* bv = (const float*)d_in[24];
  const float* ln2_g = (const float*)d_in[25];
  const float* ln2_b = (const float*)d_in[26];
  const float* W1 = (const float*)d_in[27];
  const float* b1 = (const float*)d_in[28];
  const float* W2 = (const float*)d_in[29];
  const float* b2 = (const float*)d_in[30];
  const float* lnf_g = (const float*)d_in[31];
  const float* lnf_b = (const float*)d_in[32];
  const float* W_head = (const float*)d_in[33];
  float* out = (float*)d_out;

  // workspace layout (bytes); transient region aliases dead buffers
  char* W = (char*)d_ws;
  float* x = (float*)(W + 0);                   // 5760*512 f32      11,796,480
  __bf16* h = (__bf16*)(W + 11796480);          // 5760*512 bf16      5,898,240
  __bf16* qkvT = (__bf16*)(W + 17694720);       // 6*1536*512 bf16    9,437,184
  __bf16* w1T = (__bf16*)(W + 27131904);        // 6*2048*512 bf16   12,582,912
  __bf16* w2T = (__bf16*)(W + 39714816);        // 6*512*2048 bf16   12,582,912
  __bf16* dswT = (__bf16*)(W + 52297728);       // 512*3136 bf16      3,211,264
  __bf16* c1wT = (__bf16*)(W + 55508992);       // 128*256 bf16          65,536
  __bf16* c2wT = (__bf16*)(W + 55574528);       // 128*512 bf16         131,072
  __bf16* c3wT = (__bf16*)(W + 55705600);       // 128*576 bf16         147,456
  float* whT = (float*)(W + 55853056);          // 18*512 f32            36,864
  float* bqkv = (float*)(W + 55889920);         // 6*1536 f32            36,864
  // transient region base = 55,926,784
  __bf16* c1out = (__bf16*)(W + 55926784);      // 768000*32 bf16    49,152,000
  __bf16* c2out = (__bf16*)(W + 105078784);     // 155520*64 bf16    19,906,560
  __bf16* c3out = (__bf16*)(W + 55926784);      // 94080*64 bf16     (aliases dead c1out)
  float* ste = (float*)(W + 67969024);          // 1920*512 f32      (after c3out)
  __bf16* qkvb = (__bf16*)(W + 55926784);       // 5760*1536 bf16    (aliases dead conv bufs)
  __bf16* mlph = (__bf16*)(W + 73621504);       // 5760*2048 bf16
  // end = 124,985,344 bytes

  const dim3 tb(32, 8);
  // weight transposes (BT layout) f32 -> bf16; conv1 weights absorb the /255
  transpose_pad<__bf16><<<dim3(8, 4, 1), tb, 0, stream>>>(conv1_w, c1wT, 256, 32, 128, 0, 0, 1.f / 255.f);
  transpose_pad<__bf16><<<dim3(16, 4, 1), tb, 0, stream>>>(conv2_w, c2wT, 512, 64, 128, 0, 0, 1.f);
  transpose_pad<__bf16><<<dim3(18, 4, 1), tb, 0, stream>>>(conv3_w, c3wT, 576, 64, 128, 0, 0, 1.f);
  transpose_pad<__bf16><<<dim3(98, 16, 1), tb, 0, stream>>>(dense_s_w, dswT, 3136, 512, 512, 0, 0, 1.f);
  transpose_pad<__bf16><<<dim3(16, 16, 6), tb, 0, stream>>>(Wk, qkvT, 512, 512, 512, 512 * 512, 1536 * 512, 1.f);
  transpose_pad<__bf16><<<dim3(16, 16, 6), tb, 0, stream>>>(Wq, qkvT + 512 * 512, 512, 512, 512, 512 * 512, 1536 * 512, 1.f);
  transpose_pad<__bf16><<<dim3(16, 16, 6), tb, 0, stream>>>(Wv, qkvT + 1024 * 512, 512, 512, 512, 512 * 512, 1536 * 512, 1.f);
  transpose_pad<__bf16><<<dim3(16, 64, 6), tb, 0, stream>>>(W1, w1T, 512, 2048, 2048, 512 * 2048, 2048 * 512, 1.f);
  transpose_pad<__bf16><<<dim3(64, 16, 6), tb, 0, stream>>>(W2, w2T, 2048, 512, 512, 2048 * 512, 512 * 2048, 1.f);
  transpose_pad<float><<<dim3(16, 1, 1), tb, 0, stream>>>(W_head, whT, 512, 18, 18, 0, 0, 1.f);
  biascat_k<<<6, 256, 0, stream>>>(bk, bq, bv, bqkv);

  // conv stem as implicit GEMM + dense embedding
  gemm_k<1, true, 32, 256, ACT_RELU, OUT_BF16, 32><<<dim3(6000, 1), 256, 0, stream>>>(states, c1wT, conv1_b, c1out);
  gemm_k<2, false, 64, 512, ACT_RELU, OUT_BF16, 64><<<dim3(1215, 1), 256, 0, stream>>>(c1out, c2wT, conv2_b, c2out);
  gemm_k<3, false, 64, 576, ACT_RELU, OUT_BF16, 64><<<dim3(735, 1), 256, 0, stream>>>(c2out, c3wT, conv3_b, c3out);
  gemm_k<0, false, 512, 3136, ACT_TANH, OUT_F32, 512><<<dim3(15, 4), 256, 0, stream>>>(c3out, dswT, dense_s_b, ste);

  embed_k<<<11520, 256, 0, stream>>>(rtgs, actions, timesteps, W_rtg, b_rtg, emb_a, abs_pos, rel_pos, ste, x);

  for (int i = 0; i < 6; ++i) {
    ln_k<<<1440, 256, 0, stream>>>(x, ln1_g + i * 512, ln1_b + i * 512, h);
    gemm_k<0, false, 1536, 512, ACT_NONE, OUT_BF16, 1536><<<dim3(45, 12), 256, 0, stream>>>(
        h, qkvT + (size_t)i * 1536 * 512, bqkv + i * 1536, qkvb);
    attn_k<<<512, 256, 0, stream>>>(qkvb, x);
    ln_k<<<1440, 256, 0, stream>>>(x, ln2_g + i * 512, ln2_b + i * 512, h);
    gemm_k<0, false, 2048, 512, ACT_GELU, OUT_BF16, 2048><<<dim3(45, 16), 256, 0, stream>>>(
        h, w1T + (size_t)i * 2048 * 512, b1 + i * 2048, mlph);
    gemm_k<0, false, 512, 2048, ACT_NONE, OUT_ADD, 512><<<dim3(45, 4), 256, 0, stream>>>(
        mlph, w2T + (size_t)i * 2048 * 512, b2 + i * 512, x);
  }

  head_k<<<1920, 64, 0, stream>>>(x, lnf_g, lnf_b, whT, out);
}

// Round 3
// 1391.584 us; speedup vs baseline: 1.0947x; 1.0947x over previous
//
#include <hip/hip_runtime.h>
#include <hip/hip_bf16.h>

typedef __attribute__((ext_vector_type(8))) __bf16 bf16x8;
typedef __attribute__((ext_vector_type(4))) float f32x4;

#define ACT_NONE 0
#define ACT_RELU 1
#define ACT_GELU 2
#define ACT_TANH 3
#define OUT_F32 0
#define OUT_BF16 1
#define OUT_ADD 2

// ---------------- async global->LDS, 16B per lane (lane writes lds_base + lane*16) ----------------
__device__ __forceinline__ void gll16(const void* g, void* l) {
  __builtin_amdgcn_global_load_lds(
      reinterpret_cast<const __attribute__((address_space(1))) unsigned int*>(
          reinterpret_cast<unsigned long long>(g)),
      reinterpret_cast<__attribute__((address_space(3))) unsigned int*>(
          reinterpret_cast<unsigned long long>(l)),
      16, 0, 0);
}

// ---------------- implicit-GEMM A addressing ----------------
// MODE 0: plain row-major A[M][K]
// MODE 1: conv1 im2col: input (1920,84,84,4) f32, 8x8 s4 -> k=ky*32+(kx*4+ci)
// MODE 2: conv2 im2col: input (1920,20,20,32), 4x4 s2 -> k=(ky*4+kx)*32+ci
// MODE 3: conv3 im2col: input (1920,9,9,64),  3x3 s1 -> k=(ky*3+kx)*64+ci
template<int MODE, int K>
__device__ __forceinline__ size_t a_rowbase(int m) {
  if constexpr (MODE == 0) {
    return (size_t)m * K;
  } else if constexpr (MODE == 1) {
    int img = m / 400; int p = m - img * 400; int oy = p / 20; int ox = p - oy * 20;
    return (size_t)img * 28224 + oy * 1344 + ox * 16;
  } else if constexpr (MODE == 2) {
    int img = m / 81; int p = m - img * 81; int oy = p / 9; int ox = p - oy * 9;
    return (size_t)img * 12800 + oy * 1280 + ox * 64;
  } else {
    int img = m / 49; int p = m - img * 49; int oy = p / 7; int ox = p - oy * 7;
    return (size_t)img * 5184 + oy * 576 + ox * 64;
  }
}
// wave-uniform part of im2col k-offset (lane adds lkc*8 < 32; kb is a multiple of 32,
// and 32 divides every block stride, so the division never splits a 32-chunk)
template<int MODE>
__device__ __forceinline__ int f_koff(int kb) {
  if constexpr (MODE == 0) return kb;
  else if constexpr (MODE == 2) return (kb >> 7) * 640 + ((kb >> 5) & 3) * 32;
  else return kb + (kb / 192) * 384;  // MODE 3: ky*576 + (kb - ky*192)
}

__device__ __forceinline__ bf16x8 ld8f(const float* f) {
  float4 a = *(const float4*)f;
  float4 b = *(const float4*)(f + 4);
  bf16x8 r;
  r[0] = (__bf16)a.x; r[1] = (__bf16)a.y; r[2] = (__bf16)a.z; r[3] = (__bf16)a.w;
  r[4] = (__bf16)b.x; r[5] = (__bf16)b.y; r[6] = (__bf16)b.z; r[7] = (__bf16)b.w;
  return r;
}

__device__ __forceinline__ float act_apply(float v, int ACT) {
  if (ACT == ACT_RELU) return fmaxf(v, 0.f);
  if (ACT == ACT_GELU) return 0.5f * v * (1.f + erff(v * 0.70710678118f));
  if (ACT == ACT_TANH) return tanhf(v);
  return v;
}

// ---------------- generic MFMA GEMM:  C[M][N] = act(A * BT^T + bias) ----------------
// A bf16 addressed per MODE; BT bf16 [N][K] row-major. Tile TM x TN, BK=32,
// 4 waves arranged WM x WN. global_load_lds (16B) staging, unpadded LDS rows (m97-style).
// Requires: TM%64==0, TN%64==0, (TM/16)%4==0, (TN/16)%4==0, K%32==0, all dims exact.
template<int MODE, int TM, int TN, int WM, int WN, int K, int ACT, int OUTM, int LDC>
__global__ __launch_bounds__(256) void gemm_k(const __bf16* __restrict__ A,
                                              const __bf16* __restrict__ BT,
                                              const float* __restrict__ bias,
                                              void* __restrict__ C) {
  constexpr int SM = TM / WM, SN = TN / WN;
  constexpr int AM = SM / 16, AN = SN / 16;
  constexpr int TA = TM / 64, TB = TN / 64;  // wave-insts per wave for A / B staging
  __shared__ __align__(16) __bf16 As[TM * 32];
  __shared__ __align__(16) __bf16 Bs[TN * 32];
  const int tid = threadIdx.x;
  const int wave = tid >> 6, lane = tid & 63;
  const int quad = lane >> 4, l16 = lane & 15;
  const int wr = wave % WM, wc = wave / WM;
  const int m0 = blockIdx.x * TM, n0 = blockIdx.y * TN;
  const int lrow = lane >> 2, lkc = lane & 3;  // staging: lane -> (row, 8-elem chunk)

  const __bf16* ga[TA];
  const __bf16* gb[TB];
#pragma unroll
  for (int t = 0; t < TA; ++t)
    ga[t] = A + a_rowbase<MODE, K>(m0 + (wave + 4 * t) * 16 + lrow) + lkc * 8;
#pragma unroll
  for (int t = 0; t < TB; ++t)
    gb[t] = BT + (size_t)(n0 + (wave + 4 * t) * 16 + lrow) * K + lkc * 8;

  f32x4 acc[AM][AN] = {};
  for (int kt = 0; kt < K / 32; ++kt) {
    const int kb = kt * 32;
    const int fa = f_koff<MODE>(kb);
    __syncthreads();
#pragma unroll
    for (int t = 0; t < TA; ++t)
      gll16(ga[t] + fa, &As[(wave + 4 * t) * 16 * 32]);
#pragma unroll
    for (int t = 0; t < TB; ++t)
      gll16(gb[t] + kb, &Bs[(wave + 4 * t) * 16 * 32]);
    __syncthreads();
    bf16x8 af[AM], bf[AN];
#pragma unroll
    for (int mt = 0; mt < AM; ++mt)
      af[mt] = *(const bf16x8*)&As[(wr * SM + mt * 16 + l16) * 32 + quad * 8];
#pragma unroll
    for (int nt = 0; nt < AN; ++nt)
      bf[nt] = *(const bf16x8*)&Bs[(wc * SN + nt * 16 + l16) * 32 + quad * 8];
#pragma unroll
    for (int mt = 0; mt < AM; ++mt)
#pragma unroll
      for (int nt = 0; nt < AN; ++nt)
        acc[mt][nt] = __builtin_amdgcn_mfma_f32_16x16x32_bf16(af[mt], bf[nt], acc[mt][nt], 0, 0, 0);
  }

  // epilogue: C/D layout col=lane&15, row=quad*4+reg
#pragma unroll
  for (int nt = 0; nt < AN; ++nt) {
    const int col = n0 + wc * SN + nt * 16 + l16;
    const float bvl = bias[col];
#pragma unroll
    for (int mt = 0; mt < AM; ++mt) {
#pragma unroll
      for (int r = 0; r < 4; ++r) {
        const int row = m0 + wr * SM + mt * 16 + quad * 4 + r;
        float v = act_apply(acc[mt][nt][r] + bvl, ACT);
        const size_t off = (size_t)row * LDC + col;
        if constexpr (OUTM == OUT_F32) ((float*)C)[off] = v;
        else if constexpr (OUTM == OUT_BF16) ((__bf16*)C)[off] = (__bf16)v;
        else ((float*)C)[off] += v;
      }
    }
  }
}

// ---------------- conv1: f32 A (im2col MODE 1), 128x32 tile, K=256 ----------------
__global__ __launch_bounds__(256) void conv1_k(const float* __restrict__ A,
                                               const __bf16* __restrict__ BT,
                                               const float* __restrict__ bias,
                                               __bf16* __restrict__ C) {
  __shared__ __align__(16) __bf16 As[128 * 32];
  __shared__ __align__(16) __bf16 Bs[32 * 32];
  const int tid = threadIdx.x;
  const int wave = tid >> 6, lane = tid & 63;
  const int quad = lane >> 4, l16 = lane & 15;
  const int m0 = blockIdx.x * 128;
  const int lrow = lane >> 2, lkc = lane & 3;
  const int r0 = tid >> 2, k0o = (tid & 3) * 8;  // A staging: rows r0, r0+64
  const int r1 = r0 + 64;
  const size_t ar0 = a_rowbase<1, 256>(m0 + r0);
  const size_t ar1 = a_rowbase<1, 256>(m0 + r1);
  const __bf16* gB = BT + (size_t)(wave * 16 + lrow) * 256 + lkc * 8;  // used by waves 0,1

  f32x4 acc[2][2] = {};
  bf16x8 a0 = ld8f(A + ar0 + k0o);
  bf16x8 a1 = ld8f(A + ar1 + k0o);
  for (int kt = 0; kt < 8; ++kt) {
    const int kb = kt * 32;
    __syncthreads();
    if (wave < 2) gll16(gB + kb, &Bs[wave * 16 * 32]);
    *(bf16x8*)&As[r0 * 32 + k0o] = a0;
    *(bf16x8*)&As[r1 * 32 + k0o] = a1;
    __syncthreads();
    if (kt < 7) {
      const int fa = (kt + 1) * 336;  // f32 offset for k-block kt+1 (ky stride 336 floats)
      a0 = ld8f(A + ar0 + fa + k0o);
      a1 = ld8f(A + ar1 + fa + k0o);
    }
    bf16x8 af[2], bf[2];
#pragma unroll
    for (int mt = 0; mt < 2; ++mt)
      af[mt] = *(const bf16x8*)&As[(wave * 32 + mt * 16 + l16) * 32 + quad * 8];
#pragma unroll
    for (int nt = 0; nt < 2; ++nt)
      bf[nt] = *(const bf16x8*)&Bs[(nt * 16 + l16) * 32 + quad * 8];
#pragma unroll
    for (int mt = 0; mt < 2; ++mt)
#pragma unroll
      for (int nt = 0; nt < 2; ++nt)
        acc[mt][nt] = __builtin_amdgcn_mfma_f32_16x16x32_bf16(af[mt], bf[nt], acc[mt][nt], 0, 0, 0);
  }
#pragma unroll
  for (int nt = 0; nt < 2; ++nt) {
    const int col = nt * 16 + l16;
    const float bvl = bias[col];
#pragma unroll
    for (int mt = 0; mt < 2; ++mt) {
#pragma unroll
      for (int r = 0; r < 4; ++r) {
        const int row = m0 + wave * 32 + mt * 16 + quad * 4 + r;
        C[(size_t)row * 32 + col] = (__bf16)fmaxf(acc[mt][nt][r] + bvl, 0.f);
      }
    }
  }
}

// ---------------- transpose + pad (+scale): dst[Cpad][R] = src[R][C]^T, f32 src ----------------
template<typename TO>
__global__ void transpose_pad(const float* __restrict__ src, TO* __restrict__ dst,
                              int R, int C, int Cpad, long long sz, long long dz, float scale) {
  src += blockIdx.z * sz; dst += blockIdx.z * dz;
  __shared__ float t[32][33];
  const int tx = threadIdx.x, ty = threadIdx.y;
  const int r0 = blockIdx.x * 32, c0 = blockIdx.y * 32;
  for (int i = ty; i < 32; i += 8) {
    int r = r0 + i, c = c0 + tx;
    t[i][tx] = (r < R && c < C) ? src[(size_t)r * C + c] : 0.f;
  }
  __syncthreads();
  for (int i = ty; i < 32; i += 8) {
    int c = c0 + i, r = r0 + tx;
    if (c < Cpad && r < R)
      dst[(size_t)c * R + r] = (c < C) ? (TO)(t[tx][i] * scale) : (TO)0.f;
  }
}

__global__ void biascat_k(const float* bk, const float* bq, const float* bv, float* dst) {
  const int i = blockIdx.x;
  for (int d = threadIdx.x; d < 512; d += 256) {
    dst[i * 1536 + d] = bk[i * 512 + d];
    dst[i * 1536 + 512 + d] = bq[i * 512 + d];
    dst[i * 1536 + 1024 + d] = bv[i * 512 + d];
  }
}

// ---------------- token embedding: x = interleave(rtg_e, st_e, a_e) + pos ----------------
__global__ void embed_k(const float* __restrict__ rtgs, const int* __restrict__ actions,
                        const int* __restrict__ timesteps, const float* __restrict__ W_rtg,
                        const float* __restrict__ b_rtg, const float* __restrict__ emb_a,
                        const float* __restrict__ abs_pos, const float* __restrict__ rel_pos,
                        const float* __restrict__ ste, float* __restrict__ x) {
  const int idx = blockIdx.x * 256 + threadIdx.x;  // 64*90*512 total
  const int d = idx & 511; const int rb = idx >> 9;
  const int b = rb / 90, t = rb - b * 90;
  const int l = t / 3, r = t - l * 3;
  const float pos = rel_pos[t * 512 + d] + abs_pos[(size_t)timesteps[b] * 512 + d];
  float tok;
  if (r == 0) tok = tanhf(rtgs[b * 30 + l] * W_rtg[d] + b_rtg[d]);
  else if (r == 1) tok = ste[(size_t)(b * 30 + l) * 512 + d];
  else tok = tanhf(emb_a[actions[b * 30 + l] * 512 + d]);
  x[idx] = tok + pos;
}

// ---------------- layernorm: h_bf16 = LN(x_f32) * g + b, one wave per row ----------------
__global__ __launch_bounds__(256) void ln_k(const float* __restrict__ x, const float* __restrict__ g,
                                            const float* __restrict__ bb, __bf16* __restrict__ h) {
  const int row = blockIdx.x * 4 + (threadIdx.x >> 6);
  const int lane = threadIdx.x & 63;
  const float* xr = x + (size_t)row * 512;
  float4 a = *(const float4*)&xr[lane * 8];
  float4 c = *(const float4*)&xr[lane * 8 + 4];
  float vv[8] = {a.x, a.y, a.z, a.w, c.x, c.y, c.z, c.w};
  float s = 0.f, q = 0.f;
#pragma unroll
  for (int j = 0; j < 8; ++j) { s += vv[j]; q += vv[j] * vv[j]; }
  for (int o = 32; o; o >>= 1) { s += __shfl_xor(s, o); q += __shfl_xor(q, o); }
  const float mean = s * (1.f / 512.f);
  const float var = q * (1.f / 512.f) - mean * mean;
  const float rstd = rsqrtf(var + 1e-3f);
  float4 g1 = *(const float4*)&g[lane * 8];
  float4 g2 = *(const float4*)&g[lane * 8 + 4];
  float4 b1 = *(const float4*)&bb[lane * 8];
  float4 b2 = *(const float4*)&bb[lane * 8 + 4];
  float gg[8] = {g1.x, g1.y, g1.z, g1.w, g2.x, g2.y, g2.z, g2.w};
  float bbv[8] = {b1.x, b1.y, b1.z, b1.w, b2.x, b2.y, b2.z, b2.w};
  bf16x8 ov;
#pragma unroll
  for (int j = 0; j < 8; ++j)
    ov[j] = (__bf16)((vv[j] - mean) * rstd * gg[j] + bbv[j]);
  *(bf16x8*)&h[(size_t)row * 512 + lane * 8] = ov;
}

// ---------------- fused attention per (b,h): s=K@Q^T/8 masked, softmax, o=W@V, x += o ----------------
__global__ __launch_bounds__(256) void attn_k(const __bf16* __restrict__ qkv, float* __restrict__ x) {
  __shared__ __align__(16) char smem[64512];
  __bf16* kS = (__bf16*)smem;              // [96][72]  13824B
  __bf16* qS = (__bf16*)(smem + 13824);    // [96][72]  13824B
  __bf16* wS = (__bf16*)smem;              // [96][104] 19968B (reuses k/q after scores)
  float* sS = (float*)(smem + 27648);      // [96][96]  36864B
  __bf16* vT = (__bf16*)(smem + 27648);    // [64][104] 13312B (reuses sS after softmax)

  const int tid = threadIdx.x;
  const int b = blockIdx.x >> 3, h = blockIdx.x & 7;
  const int wave = tid >> 6, lane = tid & 63, quad = lane >> 4, l16 = lane & 15;
  const size_t rowbase = (size_t)b * 90 * 1536 + h * 64;

  // phase 1: load K, Q tiles (zero-pad rows 90..95)
  for (int c = tid; c < 768; c += 256) {
    const int t = c >> 3, d8 = (c & 7) * 8;
    bf16x8 kv, qv;
#pragma unroll
    for (int j = 0; j < 8; ++j) { kv[j] = (__bf16)0.f; qv[j] = (__bf16)0.f; }
    if (t < 90) {
      const __bf16* src = qkv + rowbase + (size_t)t * 1536 + d8;
      kv = *(const bf16x8*)src;
      qv = *(const bf16x8*)(src + 512);
    }
    *(bf16x8*)&kS[t * 72 + d8] = kv;
    *(bf16x8*)&qS[t * 72 + d8] = qv;
  }
  __syncthreads();

  // phase 2: s[i][j] = sum_d k[i,d] q[j,d] / 8, causal mask j<=i
  for (int tt = wave; tt < 36; tt += 4) {
    const int it = tt / 6, jt = tt - it * 6;
    f32x4 acc = {0.f, 0.f, 0.f, 0.f};
#pragma unroll
    for (int ks = 0; ks < 2; ++ks) {
      bf16x8 af = *(const bf16x8*)&kS[(it * 16 + l16) * 72 + ks * 32 + quad * 8];
      bf16x8 bq = *(const bf16x8*)&qS[(jt * 16 + l16) * 72 + ks * 32 + quad * 8];
      acc = __builtin_amdgcn_mfma_f32_16x16x32_bf16(af, bq, acc, 0, 0, 0);
    }
    const int col = jt * 16 + l16;
#pragma unroll
    for (int r = 0; r < 4; ++r) {
      const int row = it * 16 + quad * 4 + r;
      sS[row * 96 + col] = (col <= row && col < 90) ? acc[r] * 0.125f : -1e30f;
    }
  }
  __syncthreads();

  // phase 3: row softmax -> wS (bf16)
  for (int row = wave; row < 96; row += 4) {
    const float e0 = sS[row * 96 + lane];
    const float e1 = (lane < 32) ? sS[row * 96 + 64 + lane] : -1e30f;
    float m = fmaxf(e0, e1);
    for (int o = 32; o; o >>= 1) m = fmaxf(m, __shfl_xor(m, o));
    const float p0 = __expf(e0 - m);
    const float p1 = (lane < 32) ? __expf(e1 - m) : 0.f;
    float s = p0 + p1;
    for (int o = 32; o; o >>= 1) s += __shfl_xor(s, o);
    const float inv = 1.f / s;
    wS[row * 104 + lane] = (__bf16)(p0 * inv);
    if (lane < 32) wS[row * 104 + 64 + lane] = (__bf16)(p1 * inv);
  }
  __syncthreads();

  // phase 4: load V transposed into vT[d][j] (zero-pad cols 90..95)
  for (int c = tid; c < 768; c += 256) {
    const int t = c >> 3, d8 = (c & 7) * 8;
    bf16x8 vv;
#pragma unroll
    for (int j = 0; j < 8; ++j) vv[j] = (__bf16)0.f;
    if (t < 90) vv = *(const bf16x8*)(qkv + rowbase + (size_t)t * 1536 + 1024 + d8);
#pragma unroll
    for (int j = 0; j < 8; ++j) vT[(d8 + j) * 104 + t] = vv[j];
  }
  __syncthreads();

  // phase 5: o[i][d] = sum_j w[i,j] v[j,d]; x[b, i, h*64+d] += o
  for (int tt = wave; tt < 24; tt += 4) {
    const int it = tt >> 2, dt = tt & 3;
    f32x4 acc = {0.f, 0.f, 0.f, 0.f};
#pragma unroll
    for (int ks = 0; ks < 3; ++ks) {
      bf16x8 aw = *(const bf16x8*)&wS[(it * 16 + l16) * 104 + ks * 32 + quad * 8];
      bf16x8 bv = *(const bf16x8*)&vT[(dt * 16 + l16) * 104 + ks * 32 + quad * 8];
      acc = __builtin_amdgcn_mfma_f32_16x16x32_bf16(aw, bv, acc, 0, 0, 0);
    }
    const int d = dt * 16 + l16;
#pragma unroll
    for (int r = 0; r < 4; ++r) {
      const int i = it * 16 + quad * 4 + r;
      if (i < 90) {
        float* p = x + (size_t)(b * 90 + i) * 512 + h * 64 + d;
        *p += acc[r];
      }
    }
  }
}

// ---------------- fused final LN + head (state tokens only), 1 wave per output row ----------------
__global__ __launch_bounds__(64) void head_k(const float* __restrict__ x, const float* __restrict__ g,
                                             const float* __restrict__ bb, const float* __restrict__ whT,
                                             float* __restrict__ out) {
  const int m = blockIdx.x;  // 0..1919 = b*30+l
  const int b = m / 30, l = m - b * 30;
  const float* xr = x + (size_t)(b * 90 + 3 * l + 1) * 512;
  const int lane = threadIdx.x;
  float4 a = *(const float4*)&xr[lane * 8];
  float4 c = *(const float4*)&xr[lane * 8 + 4];
  float vv[8] = {a.x, a.y, a.z, a.w, c.x, c.y, c.z, c.w};
  float s = 0.f, q = 0.f;
#pragma unroll
  for (int j = 0; j < 8; ++j) { s += vv[j]; q += vv[j] * vv[j]; }
  for (int o = 32; o; o >>= 1) { s += __shfl_xor(s, o); q += __shfl_xor(q, o); }
  const float mean = s * (1.f / 512.f);
  const float var = q * (1.f / 512.f) - mean * mean;
  const float rstd = rsqrtf(var + 1e-3f);
  float4 g1 = *(const float4*)&g[lane * 8];
  float4 g2 = *(const float4*)&g[lane * 8 + 4];
  float4 b1 = *(const float4*)&bb[lane * 8];
  float4 b2 = *(const float4*)&bb[lane * 8 + 4];
  float gg[8] = {g1.x, g1.y, g1.z, g1.w, g2.x, g2.y, g2.z, g2.w};
  float bbv[8] = {b1.x, b1.y, b1.z, b1.w, b2.x, b2.y, b2.z, b2.w};
#pragma unroll
  for (int j = 0; j < 8; ++j)
    vv[j] = (vv[j] - mean) * rstd * gg[j] + bbv[j];
  for (int aa = 0; aa < 18; ++aa) {
    float4 w1v = *(const float4*)&whT[aa * 512 + lane * 8];
    float4 w2v = *(const float4*)&whT[aa * 512 + lane * 8 + 4];
    float ww[8] = {w1v.x, w1v.y, w1v.z, w1v.w, w2v.x, w2v.y, w2v.z, w2v.w};
    float d = 0.f;
#pragma unroll
    for (int j = 0; j < 8; ++j) d += vv[j] * ww[j];
    for (int o = 32; o; o >>= 1) d += __shfl_xor(d, o);
    if (lane == 0) out[m * 18 + aa] = d;
  }
}

// ---------------- host ----------------
extern "C" void kernel_launch(void* const* d_in, const int* in_sizes, int n_in,
                              void* d_out, int out_size, void* d_ws, size_t ws_size,
                              hipStream_t stream) {
  const float* rtgs = (const float*)d_in[0];
  const float* states = (const float*)d_in[1];
  const int* actions = (const int*)d_in[2];
  const int* timesteps = (const int*)d_in[3];
  const float* W_rtg = (const float*)d_in[4];
  const float* b_rtg = (const float*)d_in[5];
  const float* conv1_w = (const float*)d_in[6];
  const float* conv1_b = (const float*)d_in[7];
  const float* conv2_w = (const float*)d_in[8];
  const float* conv2_b = (const float*)d_in[9];
  const float* conv3_w = (const float*)d_in[10];
  const float* conv3_b = (const float*)d_in[11];
  const float* dense_s_w = (const float*)d_in[12];
  const float* dense_s_b = (const float*)d_in[13];
  const float* emb_a = (const float*)d_in[14];
  const float* abs_pos = (const float*)d_in[15];
  const float* rel_pos = (const float*)d_in[16];
  const float* ln1_g = (const float*)d_in[17];
  const float* ln1_b = (const float*)d_in[18];
  const float* Wk = (const float*)d_in[19];
  const float* bk = (const float*)d_in[20];
  const float* Wq = (const float*)d_in[21];
  const float* bq = (const float*)d_in[22];
  const float* Wv = (const float*)d_in[23];
  const float* bv = (const float*)d_in[24];
  const float* ln2_g = (const float*)d_in[25];
  const float* ln2_b = (const float*)d_in[26];
  const float* W1 = (const float*)d_in[27];
  const float* b1 = (const float*)d_in[28];
  const float* W2 = (const float*)d_in[29];
  const float* b2 = (const float*)d_in[30];
  const float* lnf_g = (const float*)d_in[31];
  const float* lnf_b = (const float*)d_in[32];
  const float* W_head = (const float*)d_in[33];
  float* out = (float*)d_out;

  // workspace layout (bytes); transient region aliases dead buffers
  char* W = (char*)d_ws;
  float* x = (float*)(W + 0);                   // 5760*512 f32      11,796,480
  __bf16* h = (__bf16*)(W + 11796480);          // 5760*512 bf16      5,898,240
  __bf16* qkvT = (__bf16*)(W + 17694720);       // 6*1536*512 bf16    9,437,184
  __bf16* w1T = (__bf16*)(W + 27131904);        // 6*2048*512 bf16   12,582,912
  __bf16* w2T = (__bf16*)(W + 39714816);        // 6*512*2048 bf16   12,582,912
  __bf16* dswT = (__bf16*)(W + 52297728);       // 512*3136 bf16      3,211,264
  __bf16* c1wT = (__bf16*)(W + 55508992);       // 128*256 bf16          65,536
  __bf16* c2wT = (__bf16*)(W + 55574528);       // 128*512 bf16         131,072
  __bf16* c3wT = (__bf16*)(W + 55705600);       // 128*576 bf16         147,456
  float* whT = (float*)(W + 55853056);          // 18*512 f32            36,864
  float* bqkv = (float*)(W + 55889920);         // 6*1536 f32            36,864
  // transient region base = 55,926,784
  __bf16* c1out = (__bf16*)(W + 55926784);      // 768000*32 bf16    49,152,000
  __bf16* c2out = (__bf16*)(W + 105078784);     // 155520*64 bf16    19,906,560
  __bf16* c3out = (__bf16*)(W + 55926784);      // 94080*64 bf16     (aliases dead c1out)
  float* ste = (float*)(W + 67969024);          // 1920*512 f32      (after c3out)
  __bf16* qkvb = (__bf16*)(W + 55926784);       // 5760*1536 bf16    (aliases dead conv bufs)
  __bf16* mlph = (__bf16*)(W + 73621504);       // 5760*2048 bf16
  // end = 124,985,344 bytes

  const dim3 tb(32, 8);
  // weight transposes (BT layout) f32 -> bf16; conv1 weights absorb the /255
  transpose_pad<__bf16><<<dim3(8, 4, 1), tb, 0, stream>>>(conv1_w, c1wT, 256, 32, 128, 0, 0, 1.f / 255.f);
  transpose_pad<__bf16><<<dim3(16, 4, 1), tb, 0, stream>>>(conv2_w, c2wT, 512, 64, 128, 0, 0, 1.f);
  transpose_pad<__bf16><<<dim3(18, 4, 1), tb, 0, stream>>>(conv3_w, c3wT, 576, 64, 128, 0, 0, 1.f);
  transpose_pad<__bf16><<<dim3(98, 16, 1), tb, 0, stream>>>(dense_s_w, dswT, 3136, 512, 512, 0, 0, 1.f);
  transpose_pad<__bf16><<<dim3(16, 16, 6), tb, 0, stream>>>(Wk, qkvT, 512, 512, 512, 512 * 512, 1536 * 512, 1.f);
  transpose_pad<__bf16><<<dim3(16, 16, 6), tb, 0, stream>>>(Wq, qkvT + 512 * 512, 512, 512, 512, 512 * 512, 1536 * 512, 1.f);
  transpose_pad<__bf16><<<dim3(16, 16, 6), tb, 0, stream>>>(Wv, qkvT + 1024 * 512, 512, 512, 512, 512 * 512, 1536 * 512, 1.f);
  transpose_pad<__bf16><<<dim3(16, 64, 6), tb, 0, stream>>>(W1, w1T, 512, 2048, 2048, 512 * 2048, 2048 * 512, 1.f);
  transpose_pad<__bf16><<<dim3(64, 16, 6), tb, 0, stream>>>(W2, w2T, 2048, 512, 512, 2048 * 512, 512 * 2048, 1.f);
  transpose_pad<float><<<dim3(16, 1, 1), tb, 0, stream>>>(W_head, whT, 512, 18, 18, 0, 0, 1.f);
  biascat_k<<<6, 256, 0, stream>>>(bk, bq, bv, bqkv);

  // conv stem as implicit GEMM + dense embedding
  conv1_k<<<6000, 256, 0, stream>>>(states, c1wT, conv1_b, c1out);
  gemm_k<2, 128, 64, 2, 2, 512, ACT_RELU, OUT_BF16, 64><<<dim3(1215, 1), 256, 0, stream>>>(c1out, c2wT, conv2_b, c2out);
  gemm_k<3, 128, 64, 2, 2, 576, ACT_RELU, OUT_BF16, 64><<<dim3(735, 1), 256, 0, stream>>>(c2out, c3wT, conv3_b, c3out);
  gemm_k<0, 64, 64, 2, 2, 3136, ACT_TANH, OUT_F32, 512><<<dim3(30, 8), 256, 0, stream>>>(c3out, dswT, dense_s_b, (void*)ste);

  embed_k<<<11520, 256, 0, stream>>>(rtgs, actions, timesteps, W_rtg, b_rtg, emb_a, abs_pos, rel_pos, ste, x);

  for (int i = 0; i < 6; ++i) {
    ln_k<<<1440, 256, 0, stream>>>(x, ln1_g + i * 512, ln1_b + i * 512, h);
    gemm_k<0, 128, 128, 2, 2, 512, ACT_NONE, OUT_BF16, 1536><<<dim3(45, 12), 256, 0, stream>>>(
        h, qkvT + (size_t)i * 1536 * 512, bqkv + i * 1536, qkvb);
    attn_k<<<512, 256, 0, stream>>>(qkvb, x);
    ln_k<<<1440, 256, 0, stream>>>(x, ln2_g + i * 512, ln2_b + i * 512, h);
    gemm_k<0, 128, 128, 2, 2, 512, ACT_GELU, OUT_BF16, 2048><<<dim3(45, 16), 256, 0, stream>>>(
        h, w1T + (size_t)i * 2048 * 512, b1 + i * 2048, mlph);
    gemm_k<0, 64, 128, 2, 2, 2048, ACT_NONE, OUT_ADD, 512><<<dim3(90, 4), 256, 0, stream>>>(
        mlph, w2T + (size_t)i * 2048 * 512, b2 + i * 512, x);
  }

  head_k<<<1920, 64, 0, stream>>>(x, lnf_g, lnf_b, whT, out);
}